// Round 6
// baseline (72.337 us; speedup 1.0000x reference)
//
#include <hip/hip_runtime.h>
#include <math.h>

#define NROWS 65536
#define D 64
#define K 1024
#define BR 128            // rows per block = 4 waves x 32 rows
#define EC 128            // codes per staged chunk
#define NCH 8
#define THREADS 256
#define TAU_S 0.005f      // certification gap in s-units (dist gap = 2x)
#define LOSS_SCALE (1.25f / (65536.0f * 64.0f))

typedef short bf16x8 __attribute__((ext_vector_type(8)));
typedef float f32x4 __attribute__((ext_vector_type(4)));

__device__ inline unsigned short f2bf(float f) {
    unsigned int u = __float_as_uint(f);
    unsigned int r = u + 0x7fffu + ((u >> 16) & 1u);   // RN-even
    return (unsigned short)(r >> 16);
}
__device__ inline float bf2f(unsigned short h) {
    return __uint_as_float(((unsigned int)h) << 16);
}
__device__ inline void cvt8(const float4& a, const float4& b, bf16x8& h, bf16x8& l) {
    float f[8] = {a.x, a.y, a.z, a.w, b.x, b.y, b.z, b.w};
#pragma unroll
    for (int j = 0; j < 8; ++j) {
        unsigned short hb = f2bf(f[j]);
        h[j] = (short)hb;
        l[j] = (short)f2bf(f[j] - bf2f(hb));
    }
}

#define MFMA __builtin_amdgcn_mfma_f32_16x16x32_bf16

// prep: half-norms Ch, PRE-SWIZZLED bf16 limb frags (staging order), zero loss.
// layout: Eswz[chunk*2048 + limb*1024 + c*8 + (u8 ^ (c&7))]
__global__ void vq_prep(const float* __restrict__ E, float* __restrict__ Ch,
                        bf16x8* __restrict__ Eswz, float* __restrict__ lossp) {
    int k = blockIdx.x * blockDim.x + threadIdx.x;
    if (k == 0) *lossp = 0.f;
    if (k >= K) return;
    const float4* ev = (const float4*)(E + (size_t)k * D);
    float4 v4[16];
    float s = 0.f;
#pragma unroll
    for (int p = 0; p < 16; ++p) {
        float4 v = ev[p];
        v4[p] = v;
        s = fmaf(v.x, v.x, s); s = fmaf(v.y, v.y, s);
        s = fmaf(v.z, v.z, s); s = fmaf(v.w, v.w, s);
    }
    Ch[k] = 0.5f * s;
    int ch = k >> 7, c = k & 127, cs = c & 7;
    size_t base = (size_t)ch * 2048 + c * 8;
#pragma unroll
    for (int u8 = 0; u8 < 8; ++u8) {
        bf16x8 h, l;
        cvt8(v4[2 * u8], v4[2 * u8 + 1], h, l);
        Eswz[base + (u8 ^ cs)] = h;
        Eswz[base + 1024 + (u8 ^ cs)] = l;
    }
}

__global__ __launch_bounds__(THREADS, 2) void vq_main(
    const float* __restrict__ X, const float* __restrict__ E,
    const float* __restrict__ Chg, const bf16x8* __restrict__ Eswz,
    float* __restrict__ out, float* __restrict__ lossp)
{
    __shared__ bf16x8 sBuf[2][2048];   // 64 KB double buffer (hi: 0..1023, lo: 1024..2047)
    __shared__ float  sCh[K];          // 4 KB
    __shared__ int    sIdx[BR];
    __shared__ int    sFlag[BR];
    __shared__ int    sNf;
    __shared__ float  sLoss[4];

    const int t    = threadIdx.x;
    const int w    = t >> 6;
    const int lane = t & 63;
    const int l15  = lane & 15;
    const int l4   = lane >> 4;
    const int cs   = l15 & 7;              // swizzle const, same for every code tile
    const int o0   = l4 ^ cs;              // k-step 0 fragment slot
    const int o1   = (4 + l4) ^ cs;        // k-step 1 fragment slot

    const float4* Xg4 = (const float4*)X;
    const float4* Eg4 = (const float4*)E;

    if (t == 0) sNf = 0;
#pragma unroll
    for (int p = 0; p < 4; ++p) sCh[p * 256 + t] = Chg[p * 256 + t];

    // ---- A fragments: 32 rows/wave (2 row-tiles), straight from global ----
    bf16x8 ah[2][2], al[2][2];
#pragma unroll
    for (int rt = 0; rt < 2; ++rt) {
        size_t ab = ((size_t)blockIdx.x * BR + w * 32 + rt * 16 + l15) * 16;
#pragma unroll
        for (int kt = 0; kt < 2; ++kt) {
            float4 fa = Xg4[ab + kt * 8 + l4 * 2];
            float4 fb = Xg4[ab + kt * 8 + l4 * 2 + 1];
            cvt8(fa, fb, ah[rt][kt], al[rt][kt]);
        }
    }

    // ---- stage chunk 0 (linear copy, layout pre-swizzled in global) ----
    bf16x8 rs[8];
#pragma unroll
    for (int p = 0; p < 8; ++p) rs[p] = Eswz[p * 256 + t];
#pragma unroll
    for (int p = 0; p < 8; ++p) sBuf[0][p * 256 + t] = rs[p];
    __syncthreads();

    float m[2][4], m2[2][4]; int bk[2][4];
#pragma unroll
    for (int rt = 0; rt < 2; ++rt)
#pragma unroll
        for (int r = 0; r < 4; ++r) { m[rt][r] = -INFINITY; m2[rt][r] = -INFINITY; bk[rt][r] = 0; }

    for (int ch = 0; ch < NCH; ++ch) {
        const int cur = ch & 1;
        // T14: issue next chunk's loads EARLY; they fly during compute
        if (ch + 1 < NCH) {
#pragma unroll
            for (int p = 0; p < 8; ++p)
                rs[p] = Eswz[(size_t)(ch + 1) * 2048 + p * 256 + t];
        }
        const bf16x8* __restrict__ bufH = sBuf[cur];
        const bf16x8* __restrict__ bufL = sBuf[cur] + 1024;

#pragma unroll
        for (int g = 0; g < 4; ++g) {
            const int c0 = g * 32 + l15;        // even t8 code
            const int c1 = c0 + 16;             // odd t8 code
            float ce0 = sCh[ch * EC + c0];
            float ce1 = sCh[ch * EC + c1];
            bf16x8 bh00 = bufH[c0 * 8 + o0];
            bf16x8 bh01 = bufH[c0 * 8 + o1];
            bf16x8 bl00 = bufL[c0 * 8 + o0];
            bf16x8 bl01 = bufL[c0 * 8 + o1];
            bf16x8 bh10 = bufH[c1 * 8 + o0];
            bf16x8 bh11 = bufH[c1 * 8 + o1];
            bf16x8 bl10 = bufL[c1 * 8 + o0];
            bf16x8 bl11 = bufL[c1 * 8 + o1];

            // acc pre-loaded with -0.5||e||^2: s = dot - 0.5||e||^2 falls out of MFMA
            f32x4 a00 = {-ce0, -ce0, -ce0, -ce0};   // (c0, rt0)
            f32x4 a01 = {-ce0, -ce0, -ce0, -ce0};   // (c0, rt1)
            f32x4 a10 = {-ce1, -ce1, -ce1, -ce1};   // (c1, rt0)
            f32x4 a11 = {-ce1, -ce1, -ce1, -ce1};   // (c1, rt1)

            __builtin_amdgcn_s_setprio(1);
            a00 = MFMA(ah[0][0], bh00, a00, 0, 0, 0); a01 = MFMA(ah[1][0], bh00, a01, 0, 0, 0);
            a10 = MFMA(ah[0][0], bh10, a10, 0, 0, 0); a11 = MFMA(ah[1][0], bh10, a11, 0, 0, 0);
            a00 = MFMA(ah[0][1], bh01, a00, 0, 0, 0); a01 = MFMA(ah[1][1], bh01, a01, 0, 0, 0);
            a10 = MFMA(ah[0][1], bh11, a10, 0, 0, 0); a11 = MFMA(ah[1][1], bh11, a11, 0, 0, 0);
            a00 = MFMA(al[0][0], bh00, a00, 0, 0, 0); a01 = MFMA(al[1][0], bh00, a01, 0, 0, 0);
            a10 = MFMA(al[0][0], bh10, a10, 0, 0, 0); a11 = MFMA(al[1][0], bh10, a11, 0, 0, 0);
            a00 = MFMA(al[0][1], bh01, a00, 0, 0, 0); a01 = MFMA(al[1][1], bh01, a01, 0, 0, 0);
            a10 = MFMA(al[0][1], bh11, a10, 0, 0, 0); a11 = MFMA(al[1][1], bh11, a11, 0, 0, 0);
            a00 = MFMA(ah[0][0], bl00, a00, 0, 0, 0); a01 = MFMA(ah[1][0], bl00, a01, 0, 0, 0);
            a10 = MFMA(ah[0][0], bl10, a10, 0, 0, 0); a11 = MFMA(ah[1][0], bl10, a11, 0, 0, 0);
            a00 = MFMA(ah[0][1], bl01, a00, 0, 0, 0); a01 = MFMA(ah[1][1], bl01, a01, 0, 0, 0);
            a10 = MFMA(ah[0][1], bl11, a10, 0, 0, 0); a11 = MFMA(ah[1][1], bl11, a11, 0, 0, 0);
            __builtin_amdgcn_s_setprio(0);

            const int k0 = ch * EC + c0;
            const int k1 = ch * EC + c1;
#pragma unroll
            for (int r = 0; r < 4; ++r) {
                float v;
                v = a00[r];
                m2[0][r] = fmaxf(m2[0][r], fminf(m[0][r], v));
                bk[0][r] = (v > m[0][r]) ? k0 : bk[0][r];
                m[0][r]  = fmaxf(m[0][r], v);
                v = a01[r];
                m2[1][r] = fmaxf(m2[1][r], fminf(m[1][r], v));
                bk[1][r] = (v > m[1][r]) ? k0 : bk[1][r];
                m[1][r]  = fmaxf(m[1][r], v);
                v = a10[r];
                m2[0][r] = fmaxf(m2[0][r], fminf(m[0][r], v));
                bk[0][r] = (v > m[0][r]) ? k1 : bk[0][r];
                m[0][r]  = fmaxf(m[0][r], v);
                v = a11[r];
                m2[1][r] = fmaxf(m2[1][r], fminf(m[1][r], v));
                bk[1][r] = (v > m[1][r]) ? k1 : bk[1][r];
                m[1][r]  = fmaxf(m[1][r], v);
            }
        }

        if (ch + 1 < NCH) {
#pragma unroll
            for (int p = 0; p < 8; ++p) sBuf[cur ^ 1][p * 256 + t] = rs[p];
        }
        __syncthreads();
    }

    // ---- per-row top2 reduce across 16 col-lanes (argmax s, tie -> lower k) ----
#pragma unroll
    for (int rt = 0; rt < 2; ++rt)
#pragma unroll
        for (int r = 0; r < 4; ++r) {
            float mm = m[rt][r], mm2 = m2[rt][r]; int kk = bk[rt][r];
#pragma unroll
            for (int off = 1; off < 16; off <<= 1) {
                float om  = __shfl_xor(mm,  off, 64);
                float om2 = __shfl_xor(mm2, off, 64);
                int   ok  = __shfl_xor(kk,  off, 64);
                mm2 = fmaxf(fmaxf(mm2, om2), fminf(mm, om));
                if (om > mm || (om == mm && ok < kk)) { mm = om; kk = ok; }
            }
            if (l15 == 0) {
                int lr = w * 32 + rt * 16 + l4 * 4 + r;
                sIdx[lr] = kk;
                if (mm - mm2 < TAU_S) {
                    int pos = atomicAdd(&sNf, 1);
                    sFlag[pos] = lr;
                }
            }
        }
    __syncthreads();

    // ---- fused exact re-rank of flagged rows (one wave per row) ----
    {
        int nf = sNf;
        for (int i = w; i < nf; i += 4) {
            int lr = sFlag[i];
            size_t grow = (size_t)blockIdx.x * BR + lr;
            const float4* xr = Xg4 + grow * 16;
            float bs = -INFINITY; int bki = 0;
#pragma unroll 1
            for (int jj = 0; jj < 16; ++jj) {
                int kq = jj * 64 + lane;
                const float4* er = Eg4 + (size_t)kq * 16;
                float a0 = 0.f, a1 = 0.f, a2 = 0.f, a3 = 0.f;
#pragma unroll
                for (int p = 0; p < 16; p += 4) {
                    float4 xv0 = xr[p],     e0 = er[p];
                    float4 xv1 = xr[p + 1], e1 = er[p + 1];
                    float4 xv2 = xr[p + 2], e2 = er[p + 2];
                    float4 xv3 = xr[p + 3], e3 = er[p + 3];
                    a0 = fmaf(xv0.x, e0.x, a0); a0 = fmaf(xv0.y, e0.y, a0);
                    a0 = fmaf(xv0.z, e0.z, a0); a0 = fmaf(xv0.w, e0.w, a0);
                    a1 = fmaf(xv1.x, e1.x, a1); a1 = fmaf(xv1.y, e1.y, a1);
                    a1 = fmaf(xv1.z, e1.z, a1); a1 = fmaf(xv1.w, e1.w, a1);
                    a2 = fmaf(xv2.x, e2.x, a2); a2 = fmaf(xv2.y, e2.y, a2);
                    a2 = fmaf(xv2.z, e2.z, a2); a2 = fmaf(xv2.w, e2.w, a2);
                    a3 = fmaf(xv3.x, e3.x, a3); a3 = fmaf(xv3.y, e3.y, a3);
                    a3 = fmaf(xv3.z, e3.z, a3); a3 = fmaf(xv3.w, e3.w, a3);
                }
                float sv = ((a0 + a1) + (a2 + a3)) - sCh[kq];
                if (sv > bs) { bs = sv; bki = kq; }   // kq ascending per lane
            }
#pragma unroll
            for (int off = 1; off < 64; off <<= 1) {
                float ob = __shfl_xor(bs, off, 64);
                int  okk = __shfl_xor(bki, off, 64);
                if (ob > bs || (ob == bs && okk < bki)) { bs = ob; bki = okk; }
            }
            if (lane == 0) sIdx[lr] = bki;
        }
    }
    __syncthreads();

    // ---- output gather + loss (2 threads per row) ----
    {
        int row = t >> 1, half = t & 1;
        int kb = sIdx[row];
        size_t grow = (size_t)blockIdx.x * BR + row;
        const float4* eq   = Eg4 + (size_t)kb * 16;
        const float4* xrow = Xg4 + grow * 16;
        float4* orow = (float4*)out + grow * 16;
        float ls = 0.f;
#pragma unroll
        for (int j = 0; j < 8; ++j) {
            int u = half * 8 + j;
            float4 qv = eq[u];
            float4 xv = xrow[u];
            orow[u] = qv;
            float dx = qv.x - xv.x; ls = fmaf(dx, dx, ls);
            float dy = qv.y - xv.y; ls = fmaf(dy, dy, ls);
            float dz = qv.z - xv.z; ls = fmaf(dz, dz, ls);
            float dw = qv.w - xv.w; ls = fmaf(dw, dw, ls);
        }
#pragma unroll
        for (int off = 32; off > 0; off >>= 1) ls += __shfl_down(ls, off, 64);
        if (lane == 0) sLoss[w] = ls;
        __syncthreads();
        if (t == 0)
            atomicAdd(lossp, (sLoss[0] + sLoss[1] + sLoss[2] + sLoss[3]) * LOSS_SCALE);
    }
}

extern "C" void kernel_launch(void* const* d_in, const int* in_sizes, int n_in,
                              void* d_out, int out_size, void* d_ws, size_t ws_size,
                              hipStream_t stream) {
    const float* X = (const float*)d_in[0];        // [64,1024,64] f32
    const float* E = (const float*)d_in[1];        // [1024,64] f32
    float* out   = (float*)d_out;
    float* lossp = out + (size_t)NROWS * D;

    // ws layout (4-byte units): Ch[1024], then Eswz (16384 bf16x8 = 256 KB)
    float*  Ch   = (float*)d_ws;
    bf16x8* Eswz = (bf16x8*)((float*)d_ws + 1024);

    vq_prep<<<(K + 255) / 256, 256, 0, stream>>>(E, Ch, Eswz, lossp);

    vq_main<<<NROWS / BR, THREADS, 0, stream>>>(
        X, E, Ch, Eswz, out, lossp);
}